// Round 13
// baseline (144.734 us; speedup 1.0000x reference)
//
#include <hip/hip_runtime.h>
#include <hip/hip_bf16.h>
#include <cstdint>

#define DI __device__ __forceinline__

using u16x8  = __attribute__((ext_vector_type(8))) unsigned short;
using u32x4  = __attribute__((ext_vector_type(4))) unsigned int;
using bf16x8 = __attribute__((ext_vector_type(8))) __bf16;
using f32x4  = __attribute__((ext_vector_type(4))) float;

// ---------- helpers ----------

DI unsigned short f2bf(float f) {           // RNE float -> bf16 bits
  unsigned u = __builtin_bit_cast(unsigned, f);
  u += 0x7fffu + ((u >> 16) & 1u);
  return (unsigned short)(u >> 16);
}
DI float bf2f(unsigned short b) {
  unsigned u = (unsigned)b << 16;
  return __builtin_bit_cast(float, u);
}
DI unsigned cvt_pk_bf16(float lo, float hi) {   // packed {lo,hi} -> 2xbf16 (no builtin on gfx950)
  unsigned r;
  asm("v_cvt_pk_bf16_f32 %0, %1, %2" : "=v"(r) : "v"(lo), "v"(hi));
  return r;
}
// gfx950 cross-lane swaps (both operands read-write):
DI void permlane_swap32(unsigned& a, unsigned& b) {
  asm("v_permlane32_swap_b32 %0, %1" : "+v"(a), "+v"(b));
}
DI void permlane_swap16(unsigned& a, unsigned& b) {
  asm("v_permlane16_swap_b32 %0, %1" : "+v"(a), "+v"(b));
}

DI void gld_lds16(const void* g, void* l) { // async global->LDS, 16B/lane
  __builtin_amdgcn_global_load_lds(
      (const __attribute__((address_space(1))) void*)(uintptr_t)g,
      (__attribute__((address_space(3))) void*)(uint32_t)(uintptr_t)l,
      16, 0, 0);
}

// counted-vmcnt waits (T4). Issued BEFORE a raw s_barrier so that after the
// barrier, every wave's loads older than the N newest are LDS-visible.
DI void wait_vm8() { asm volatile("s_waitcnt vmcnt(8)" ::: "memory"); }
DI void wait_vm4() { asm volatile("s_waitcnt vmcnt(4)" ::: "memory"); }
DI void wait_vm0() { asm volatile("s_waitcnt vmcnt(0)" ::: "memory"); }
DI void sched_fence() { asm volatile("" ::: "memory"); }

// ---------- conversion kernels ----------

__global__ __launch_bounds__(256) void cvt_bf16_kernel(const float* __restrict__ in,
                                                        unsigned short* __restrict__ out, int n) {
  int i = (blockIdx.x * 256 + threadIdx.x) * 8;
  if (i >= n) return;
  float4 v0 = *(const float4*)(in + i);
  float4 v1 = *(const float4*)(in + i + 4);
  u16x8 o;
  o[0] = f2bf(v0.x); o[1] = f2bf(v0.y); o[2] = f2bf(v0.z); o[3] = f2bf(v0.w);
  o[4] = f2bf(v1.x); o[5] = f2bf(v1.y); o[6] = f2bf(v1.z); o[7] = f2bf(v1.w);
  *(u16x8*)(out + i) = o;
}

// in[K][N] fp32 -> out[N][K] bf16
__global__ __launch_bounds__(256) void transpose_cvt_kernel(const float* __restrict__ in,
                                                             unsigned short* __restrict__ out,
                                                             int K, int N) {
  __shared__ float tile[32][33];
  int n0 = blockIdx.x * 32, k0 = blockIdx.y * 32;
  int tx = threadIdx.x & 31, ty = threadIdx.x >> 5;
#pragma unroll
  for (int i = 0; i < 4; ++i)
    tile[ty * 4 + i][tx] = in[(size_t)(k0 + ty * 4 + i) * N + n0 + tx];
  __syncthreads();
#pragma unroll
  for (int i = 0; i < 4; ++i)
    out[(size_t)(n0 + ty * 4 + i) * K + k0 + tx] = f2bf(tile[tx][ty * 4 + i]);
}

// ---------- epilogue helpers for gemm256_qkv (rule #20: static acc indices) ----------

template <int MT>
DI void rope_rows(const f32x4 (&acc)[8][4], unsigned short* __restrict__ dst,
                  int gm0, int h, float qs, int r15, int g4) {
#pragma unroll
  for (int r = 0; r < 4; ++r) {
    int mrow = gm0 + MT * 16 + g4 * 4 + r;
    int b = mrow >> 11, t = mrow & 2047;
    unsigned short* rowp = dst + (((size_t)(b * 16 + h) * 2048 + t) << 6);
    float tf = (float)t;
#pragma unroll
    for (int nt = 0; nt < 2; ++nt) {              // d in [0,32); reg nt+2 holds d+32
      int j = nt * 16 + r15;
      float invf = exp2f((float)j * -0.4152410118609203f);  // 10000^(-j/32)
      float ang = tf * invf;
      float sv, cv;
      sincosf(ang, &sv, &cv);
      float x1 = acc[MT][nt][r], x2 = acc[MT][nt + 2][r];
      rowp[j]      = f2bf((x1 * cv - x2 * sv) * qs);
      rowp[j + 32] = f2bf((x2 * cv + x1 * sv) * qs);
    }
  }
}

template <int P>
DI void vtrans_pass(const f32x4 (&acc)[8][4], short* __restrict__ tb,
                    unsigned short* __restrict__ vhead, int t0, int lane, int r15, int g4) {
#pragma unroll
  for (int np = 0; np < 2; ++np)
#pragma unroll
    for (int mt = 0; mt < 8; ++mt)
#pragma unroll
      for (int pr = 0; pr < 2; ++pr) {
        unsigned pk = cvt_pk_bf16(acc[mt][2 * P + np][2 * pr], acc[mt][2 * P + np][2 * pr + 1]);
        *(unsigned*)(tb + (np * 16 + r15) * 136 + mt * 16 + g4 * 4 + pr * 2) = pk;
      }
#pragma unroll
  for (int cc = 0; cc < 8; ++cc) {
    int dl = (cc & 3) * 8 + (lane >> 3);
    int tc = (lane & 7) * 8 + (cc >> 2) * 64;
    u16x8 vv = *(const u16x8*)(tb + dl * 136 + tc);
    *(u16x8*)(vhead + (size_t)(P * 32 + dl) * 2048 + t0 + tc) = vv;
  }
}

// ---------- QKV GEMM, 256x256 tile, BK=32, 4-slot counted-vmcnt pipeline (T3+T4) ----------

__global__ __launch_bounds__(512, 2)
void gemm256_qkv(const unsigned short* __restrict__ A, const unsigned short* __restrict__ B,
                 unsigned short* __restrict__ q_out, unsigned short* __restrict__ k_out,
                 unsigned short* __restrict__ v_out, int M, int N, int K) {
  __shared__ __align__(16) char smem[4][32768];
  const int tid = threadIdx.x;
  const int lane = tid & 63, wave = tid >> 6;        // 8 waves
  const int wr = wave >> 2, wc = wave & 3;           // 2 x 4 wave grid
  const int r15 = lane & 15, g4 = lane >> 4;

  // bijective XCD swizzle: 192 = 8 * 24; XCD x -> m-tile pair {2x, 2x+1}
  const int id = blockIdx.x;
  const int g = (id & 7) * 24 + (id >> 3);
  const int by = g / 12, bx = g % 12;
  const int m0 = by << 8, n0 = bx << 8;

  const size_t Ks = (size_t)K;
  const unsigned short* aptr = A + (size_t)(m0 + wave * 32 + r15) * Ks + g4 * 8;
  const unsigned short* bptr = B + (size_t)(n0 + wave * 32 + r15) * Ks + g4 * 8;

  f32x4 acc[8][4] = {};
  const int NT = K >> 5;                             // 32

  auto stage = [&](int slot, int tt) {
    const unsigned short* ak = aptr + tt * 32;
    const unsigned short* bk = bptr + tt * 32;
    char* sA = &smem[slot][0]     + wave * 2048;
    char* sB = &smem[slot][16384] + wave * 2048;
    gld_lds16(ak,           sA);
    gld_lds16(ak + 16 * Ks, sA + 1024);
    gld_lds16(bk,           sB);
    gld_lds16(bk + 16 * Ks, sB + 1024);
  };

  auto body = [&](int t) {                            // after wait+barrier
    sched_fence();
    const char* sA = &smem[t & 3][0];
    const char* sB = &smem[t & 3][16384];
    bf16x8 af[8], bfr[4];
#pragma unroll
    for (int mt = 0; mt < 8; ++mt)
      af[mt] = *(const bf16x8*)(sA + (wr * 8 + mt) * 1024 + lane * 16);
#pragma unroll
    for (int nt = 0; nt < 4; ++nt)
      bfr[nt] = *(const bf16x8*)(sB + (wc * 4 + nt) * 1024 + lane * 16);
    if (t + 3 < NT) stage((t + 3) & 3, t + 3);
    __builtin_amdgcn_s_setprio(1);
#pragma unroll
    for (int mt = 0; mt < 8; ++mt)
#pragma unroll
      for (int nt = 0; nt < 4; ++nt)
        acc[mt][nt] = __builtin_amdgcn_mfma_f32_16x16x32_bf16(af[mt], bfr[nt], acc[mt][nt], 0, 0, 0);
    __builtin_amdgcn_s_setprio(0);
  };

  stage(0, 0); stage(1, 1); stage(2, 2);              // prologue: depth-3 prefetch
  for (int t = 0; t < NT - 2; ++t) {
    wait_vm8();
    __builtin_amdgcn_s_barrier();
    body(t);
  }
  wait_vm4();
  __builtin_amdgcn_s_barrier();
  body(NT - 2);
  wait_vm0();
  __builtin_amdgcn_s_barrier();
  body(NT - 1);

  __syncthreads();                                    // drain before smem reuse (epilogue)

  const int gm0 = m0 + wr * 128, gn0 = n0 + wc * 64;
  const int region = gn0 >> 10;                       // 0=q 1=k 2=v
  const int h = (gn0 & 1023) >> 6;
  if (region <= 1) {
    unsigned short* dst = (region == 0) ? q_out : k_out;
    const float qs = (region == 0) ? (0.125f * 1.44269504088896341f) : 1.0f;
    rope_rows<0>(acc, dst, gm0, h, qs, r15, g4);
    rope_rows<1>(acc, dst, gm0, h, qs, r15, g4);
    rope_rows<2>(acc, dst, gm0, h, qs, r15, g4);
    rope_rows<3>(acc, dst, gm0, h, qs, r15, g4);
    rope_rows<4>(acc, dst, gm0, h, qs, r15, g4);
    rope_rows<5>(acc, dst, gm0, h, qs, r15, g4);
    rope_rows<6>(acc, dst, gm0, h, qs, r15, g4);
    rope_rows<7>(acc, dst, gm0, h, qs, r15, g4);
  } else {
    const int b = gm0 >> 11, t0 = gm0 & 2047;
    unsigned short* vhead = v_out + ((size_t)(b * 16 + h) * 64) * 2048;
    short* tb = (short*)(&smem[0][0] + wave * 16384);
    vtrans_pass<0>(acc, tb, vhead, t0, lane, r15, g4);
    vtrans_pass<1>(acc, tb, vhead, t0, lane, r15, g4);
  }
}

// ---------- out-proj GEMM: 128x128 tile, BK=32, same 4-slot counted-vmcnt pipeline ----------

__global__ __launch_bounds__(256, 2)
void gemm_proj(const unsigned short* __restrict__ A, const unsigned short* __restrict__ B,
               float* __restrict__ c_out, int M, int N, int K) {
  __shared__ __align__(16) char smem[4][16384];
  const int tid = threadIdx.x;
  const int lane = tid & 63, wave = tid >> 6;         // 4 waves
  const int wm = wave >> 1, wn = wave & 1;
  const int r15 = lane & 15, g4 = lane >> 4;

  const int id = blockIdx.x;                          // 256 blocks: XCD band swizzle
  const int xcd = id & 7, rr = id >> 3;
  const int m0 = rr << 7, n0 = xcd << 7;

  const size_t Ks = (size_t)K;
  const unsigned short* aptr = A + (size_t)(m0 + wave * 32 + r15) * Ks + g4 * 8;
  const unsigned short* bptr = B + (size_t)(n0 + wave * 32 + r15) * Ks + g4 * 8;

  f32x4 acc[4][4] = {};
  const int NT = K >> 5;                              // 32

  auto stage = [&](int slot, int tt) {
    const unsigned short* ak = aptr + tt * 32;
    const unsigned short* bk = bptr + tt * 32;
    char* sA = &smem[slot][0]    + wave * 2048;
    char* sB = &smem[slot][8192] + wave * 2048;
    gld_lds16(ak,           sA);
    gld_lds16(ak + 16 * Ks, sA + 1024);
    gld_lds16(bk,           sB);
    gld_lds16(bk + 16 * Ks, sB + 1024);
  };

  auto body = [&](int t) {
    sched_fence();
    const char* sA = &smem[t & 3][0];
    const char* sB = &smem[t & 3][8192];
    bf16x8 af[4], bfr[4];
#pragma unroll
    for (int mt = 0; mt < 4; ++mt)
      af[mt] = *(const bf16x8*)(sA + (wm * 4 + mt) * 1024 + lane * 16);
#pragma unroll
    for (int nt = 0; nt < 4; ++nt)
      bfr[nt] = *(const bf16x8*)(sB + (wn * 4 + nt) * 1024 + lane * 16);
    if (t + 3 < NT) stage((t + 3) & 3, t + 3);
    __builtin_amdgcn_s_setprio(1);
#pragma unroll
    for (int mt = 0; mt < 4; ++mt)
#pragma unroll
      for (int nt = 0; nt < 4; ++nt)
        acc[mt][nt] = __builtin_amdgcn_mfma_f32_16x16x32_bf16(af[mt], bfr[nt], acc[mt][nt], 0, 0, 0);
    __builtin_amdgcn_s_setprio(0);
  };

  stage(0, 0); stage(1, 1); stage(2, 2);
  for (int t = 0; t < NT - 2; ++t) {
    wait_vm8();
    __builtin_amdgcn_s_barrier();
    body(t);
  }
  wait_vm4();
  __builtin_amdgcn_s_barrier();
  body(NT - 2);
  wait_vm0();
  __builtin_amdgcn_s_barrier();
  body(NT - 1);

  const int gm0 = m0 + wm * 64, gn0 = n0 + wn * 64;
#pragma unroll
  for (int mt = 0; mt < 4; ++mt)
#pragma unroll
    for (int r = 0; r < 4; ++r) {
      int mrow = gm0 + mt * 16 + g4 * 4 + r;
      float* rowp = c_out + (size_t)mrow * N + gn0;
#pragma unroll
      for (int nt = 0; nt < 4; ++nt)
        rowp[nt * 16 + r15] = acc[mt][nt][r];
    }
}

// ---------- causal flash attention, v7 ----------
// v6 math (swapped QK^T, in-register softmax, cvt_pk+permlane repack, T13 defer-max,
// LPT slot packing) with the K/V staging moved to a 3-slot counted-vmcnt pipeline
// (T3+T4, proven on the GEMMs this round): depth-2 prefetch, wait vmcnt(4) + raw
// s_barrier per tile, vmcnt(0) only at the last tile. Slot (i+2)%3 == (i-1)%3 is
// safe to overwrite after barrier i (all waves' tile i-1 LDS reads complete before
// their tile i-1 MFMAs, which precede barrier i; causal-skip waves never read).
// LDS 3 x 16 KB = 48 KB -> still 3 blocks/CU.

__device__ const int RBMAP[24] = {7, 23, 20, 21, 18, 19, 17, 5,
                                  22, 6, 16, 12, 13, 14, 15, 10,
                                  0, 1, 2, 3, 8, 9, 4, 11};

__global__ __launch_bounds__(256)
void attn_fused(const unsigned short* __restrict__ qb, const unsigned short* __restrict__ kb,
                const unsigned short* __restrict__ vt, unsigned short* __restrict__ attno,
                unsigned short* __restrict__ pO, float* __restrict__ pml) {
  __shared__ __align__(16) char ksm[3][8192];
  __shared__ __align__(16) char vsm[3][8192];

  const int tid = threadIdx.x, lane = tid & 63, wave = tid >> 6;
  const int r15 = lane & 15, g4 = lane >> 4;

  const int wg = blockIdx.x;                  // 0..767
  const int qq = wg >> 3;                     // 0..95
  const int bh = (wg & 7) * 4 + qq / 24;
  const int rb = RBMAP[qq % 24];
  int J, c; bool multi;
  if (rb < 8) { J = rb; c = 0; multi = false; }
  else { int rr = rb - 8; J = 8 + (rr >> 1); c = rr & 1; multi = true; }
  const int ntw = 2 * J + 2;
  const int ktmid = J + 1;
  const int kt0 = (multi && c) ? ktmid : 0;
  const int ktN = multi ? (c ? ntw : ktmid) : ntw;
  const int NTW = ktN - kt0;
  const int q0 = J << 7;
  const int q0w = q0 + wave * 32;

  const size_t hb = (size_t)bh * 2048 * 64;
  const unsigned short* Qp = qb + hb;
  const unsigned short* Kp = kb + hb;
  const unsigned short* Vp = vt + hb;         // [64][2048]

  bf16x8 qf[2][2];
#pragma unroll
  for (int mq = 0; mq < 2; ++mq)
#pragma unroll
    for (int kc = 0; kc < 2; ++kc)
      qf[mq][kc] = *(const bf16x8*)(Qp + (size_t)(q0w + mq * 16 + r15) * 64 + kc * 32 + g4 * 8);

  f32x4 o[2][4] = {};
  float mr[2] = {-INFINITY, -INFINITY};
  float lr[2] = {0.f, 0.f};

  // stage tile kt into slot: 4 gld_lds/thread (2 K-frags + 2 V-frags per wave)
  auto stage = [&](int slot, int kt) {
    const int kv0 = kt << 6;
#pragma unroll
    for (int i = 0; i < 2; ++i) {
      int f = wave * 2 + i;
      int nt = f >> 1, kc = f & 1;
      gld_lds16(Kp + (size_t)(kv0 + nt * 16 + r15) * 64 + kc * 32 + g4 * 8, &ksm[slot][f * 1024]);
      gld_lds16(Vp + (size_t)(nt * 16 + r15) * 2048 + kv0 + kc * 32 + g4 * 8, &vsm[slot][f * 1024]);
    }
  };

  auto process = [&](int slot, int kv0, bool mask) {
    bf16x8 kf[8];
#pragma unroll
    for (int i = 0; i < 8; ++i)
      kf[i] = *(const bf16x8*)(&ksm[slot][i * 1024] + lane * 16);

    f32x4 s[4][2] = {};
    __builtin_amdgcn_s_setprio(1);
#pragma unroll
    for (int nt = 0; nt < 4; ++nt)
#pragma unroll
      for (int kc = 0; kc < 2; ++kc) {
        s[nt][0] = __builtin_amdgcn_mfma_f32_16x16x32_bf16(kf[nt * 2 + kc], qf[0][kc], s[nt][0], 0, 0, 0);
        s[nt][1] = __builtin_amdgcn_mfma_f32_16x16x32_bf16(kf[nt * 2 + kc], qf[1][kc], s[nt][1], 0, 0, 0);
      }
    __builtin_amdgcn_s_setprio(0);

    if (mask) {
#pragma unroll
      for (int nt = 0; nt < 4; ++nt)
#pragma unroll
        for (int mq = 0; mq < 2; ++mq)
#pragma unroll
          for (int r = 0; r < 4; ++r)
            if (kv0 + nt * 16 + g4 * 4 + r > q0w + mq * 16 + r15) s[nt][mq][r] = -1e9f;
    }

    bf16x8 pa[2][2];
#pragma unroll
    for (int mq = 0; mq < 2; ++mq) {
      float m0 = fmaxf(fmaxf(s[0][mq][0], s[0][mq][1]), fmaxf(s[0][mq][2], s[0][mq][3]));
      float m1 = fmaxf(fmaxf(s[1][mq][0], s[1][mq][1]), fmaxf(s[1][mq][2], s[1][mq][3]));
      float m2 = fmaxf(fmaxf(s[2][mq][0], s[2][mq][1]), fmaxf(s[2][mq][2], s[2][mq][3]));
      float m3 = fmaxf(fmaxf(s[3][mq][0], s[3][mq][1]), fmaxf(s[3][mq][2], s[3][mq][3]));
      float mx = fmaxf(fmaxf(m0, m1), fmaxf(m2, m3));
      mx = fmaxf(mx, __shfl_xor(mx, 16));
      mx = fmaxf(mx, __shfl_xor(mx, 32));
      float mnew;
      if (!__all(mx <= mr[mq] + 8.f)) {
        mnew = fmaxf(mr[mq], mx);
        float fsc = exp2f(mr[mq] - mnew);
        mr[mq] = mnew;
        lr[mq] *= fsc;
#pragma unroll
        for (int r = 0; r < 4; ++r) {
          float fr = __shfl(fsc, (g4 << 2) + r);
#pragma unroll
          for (int dt = 0; dt < 4; ++dt) o[mq][dt][r] *= fr;
        }
      } else {
        mnew = mr[mq];
      }
      float t0 = 0.f, t1 = 0.f, t2 = 0.f, t3 = 0.f;
#pragma unroll
      for (int nt = 0; nt < 4; ++nt) {
        float p0 = exp2f(s[nt][mq][0] - mnew);
        float p1 = exp2f(s[nt][mq][1] - mnew);
        float p2 = exp2f(s[nt][mq][2] - mnew);
        float p3 = exp2f(s[nt][mq][3] - mnew);
        s[nt][mq][0] = p0; s[nt][mq][1] = p1; s[nt][mq][2] = p2; s[nt][mq][3] = p3;
        if (nt == 0) t0 = (p0 + p1) + (p2 + p3);
        if (nt == 1) t1 = (p0 + p1) + (p2 + p3);
        if (nt == 2) t2 = (p0 + p1) + (p2 + p3);
        if (nt == 3) t3 = (p0 + p1) + (p2 + p3);
      }
      float ps = (t0 + t1) + (t2 + t3);
      ps += __shfl_xor(ps, 16);
      ps += __shfl_xor(ps, 32);
      lr[mq] += ps;
      unsigned p32[4][2];
#pragma unroll
      for (int nt = 0; nt < 4; ++nt) {
        p32[nt][0] = cvt_pk_bf16(s[nt][mq][0], s[nt][mq][1]);
        p32[nt][1] = cvt_pk_bf16(s[nt][mq][2], s[nt][mq][3]);
      }
#pragma unroll
      for (int kc = 0; kc < 2; ++kc) {
        u32x4 w;
#pragma unroll
        for (int pi = 0; pi < 2; ++pi) {
          unsigned a = p32[2 * kc][pi], b = p32[2 * kc + 1][pi];
          permlane_swap32(a, b);
          permlane_swap16(a, b);
          w[pi] = a;
          w[2 + pi] = b;
        }
        pa[mq][kc] = __builtin_bit_cast(bf16x8, w);
      }
    }

    bf16x8 vf[8];
#pragma unroll
    for (int i = 0; i < 8; ++i)
      vf[i] = *(const bf16x8*)(&vsm[slot][i * 1024] + lane * 16);

    __builtin_amdgcn_s_setprio(1);
#pragma unroll
    for (int kc = 0; kc < 2; ++kc)
#pragma unroll
      for (int dt = 0; dt < 4; ++dt) {
        o[0][dt] = __builtin_amdgcn_mfma_f32_16x16x32_bf16(pa[0][kc], vf[dt * 2 + kc], o[0][dt], 0, 0, 0);
        o[1][dt] = __builtin_amdgcn_mfma_f32_16x16x32_bf16(pa[1][kc], vf[dt * 2 + kc], o[1][dt], 0, 0, 0);
      }
    __builtin_amdgcn_s_setprio(0);
  };

  // 3-slot counted-vmcnt pipeline, depth-2 prefetch
  stage(0, kt0);
  if (NTW > 1) stage(1, kt0 + 1);
  for (int i = 0; i < NTW; ++i) {
    if (i + 1 < NTW) wait_vm4(); else wait_vm0();
    __builtin_amdgcn_s_barrier();
    sched_fence();
    if (i + 2 < NTW) stage((i + 2) % 3, kt0 + i + 2);
    const int kv0 = (kt0 + i) << 6;
    if (kv0 <= q0w + 31)
      process(i % 3, kv0, kv0 + 63 > q0w);
  }

  if (!multi) {
    const int b = bh >> 4, h = bh & 15;
#pragma unroll
    for (int mq = 0; mq < 2; ++mq) {
      float inv = 1.f / lr[mq];
#pragma unroll
      for (int r = 0; r < 4; ++r) {
        float ir = __shfl(inv, (g4 << 2) + r);
        int q = q0w + mq * 16 + g4 * 4 + r;
        unsigned short* rowp = attno + (size_t)(b * 2048 + q) * 1024 + h * 64;
#pragma unroll
        for (int dt = 0; dt < 4; ++dt)
          rowp[dt * 16 + r15] = f2bf(o[mq][dt][r] * ir);
      }
    }
  } else {
    const int sidx = (bh * 8 + (J - 8)) * 2 + c;
    unsigned short* po = pO + (size_t)sidx * 8192 + wave * 32 * 64;
#pragma unroll
    for (int mq = 0; mq < 2; ++mq)
#pragma unroll
      for (int r = 0; r < 4; ++r)
#pragma unroll
        for (int dt = 0; dt < 4; ++dt)
          po[(mq * 16 + g4 * 4 + r) * 64 + dt * 16 + r15] = f2bf(o[mq][dt][r]);
    if (g4 == 0) {
      float* pm = pml + sidx * 256 + wave * 32;
#pragma unroll
      for (int mq = 0; mq < 2; ++mq) {
        pm[mq * 16 + r15] = mr[mq];
        pm[128 + mq * 16 + r15] = lr[mq];
      }
    }
  }
}

// ---------- combine partials for q-blocks J>=8 (2 chunks each) ----------
__global__ __launch_bounds__(256)
void attn_combine(const unsigned short* __restrict__ pO, const float* __restrict__ pml,
                  unsigned short* __restrict__ attno) {
  const int bx = blockIdx.x;                 // 0..255 = 32 bh x 8 Jrel
  const int bh = bx >> 3, Jrel = bx & 7, J = 8 + Jrel;
  const int t = threadIdx.x;
  const int row = t >> 1;
  const int dh = (t & 1) << 5;
  const int s0i = (bh * 8 + Jrel) * 2;
  const float* pm0 = pml + s0i * 256;
  const float* pm1 = pm0 + 256;
  float m0 = pm0[row], l0 = pm0[128 + row];
  float m1 = pm1[row], l1 = pm1[128 + row];
  float mg = fmaxf(m0, m1);
  float s0 = exp2f(m0 - mg), s1 = exp2f(m1 - mg);
  float inv = 1.f / (l0 * s0 + l1 * s1);
  s0 *= inv; s1 *= inv;
  const unsigned short* o0 = pO + (size_t)s0i * 8192 + row * 64 + dh;
  const unsigned short* o1 = o0 + 8192;
  const int b = bh >> 4, h = bh & 15;
  const int q = J * 128 + row;
  unsigned short* dst = attno + (size_t)(b * 2048 + q) * 1024 + h * 64 + dh;
#pragma unroll
  for (int dd = 0; dd < 32; dd += 8) {
    u16x8 a = *(const u16x8*)(o0 + dd);
    u16x8 bq = *(const u16x8*)(o1 + dd);
    u16x8 ov;
#pragma unroll
    for (int e = 0; e < 8; ++e)
      ov[e] = f2bf(bf2f(a[e]) * s0 + bf2f(bq[e]) * s1);
    *(u16x8*)(dst + dd) = ov;
  }
}

// ---------- launcher ----------

extern "C" void kernel_launch(void* const* d_in, const int* in_sizes, int n_in,
                              void* d_out, int out_size, void* d_ws, size_t ws_size,
                              hipStream_t stream) {
  const float* x     = (const float*)d_in[0];
  const float* w_qkv = (const float*)d_in[1];
  const float* w_out = (const float*)d_in[2];
  float* out = (float*)d_out;

  char* ws = (char*)d_ws;
  unsigned short* xb  = (unsigned short*)(ws);                     // 8 MB  x bf16 (dead after gemm_qkv)
  unsigned short* wqT = (unsigned short*)(ws + (8u << 20));        // 6 MB  w_qkv^T (dead after gemm_qkv)
  unsigned short* woT = (unsigned short*)(ws + (14u << 20));       // 2 MB  w_out^T
  unsigned short* qb  = (unsigned short*)(ws + (16u << 20));       // 8 MB  q (roped, scaled)
  unsigned short* kb  = (unsigned short*)(ws + (24u << 20));       // 8 MB  k (roped)
  unsigned short* vt  = (unsigned short*)(ws + (32u << 20));       // 8 MB  v transposed [32][64][2048]
  unsigned short* ao  = (unsigned short*)(ws + (40u << 20));       // 8 MB  attn out [4096][1024]
  unsigned short* pO  = xb;                                        // partial O bf16 (8 MB, reuse)
  float*          pml = (float*)wqT;                               // partial m/l f32 (512 KB, reuse)

  cvt_bf16_kernel<<<2048, 256, 0, stream>>>(x, xb, 4096 * 1024);
  transpose_cvt_kernel<<<dim3(96, 32), 256, 0, stream>>>(w_qkv, wqT, 1024, 3072);
  transpose_cvt_kernel<<<dim3(32, 32), 256, 0, stream>>>(w_out, woT, 1024, 1024);
  gemm256_qkv<<<192, 512, 0, stream>>>(xb, wqT, qb, kb, vt, 4096, 3072, 1024);
  attn_fused<<<768, 256, 0, stream>>>(qb, kb, vt, ao, pO, pml);
  attn_combine<<<256, 256, 0, stream>>>(pO, pml, ao);
  gemm_proj<<<256, 256, 0, stream>>>(ao, woT, out, 4096, 1024, 1024);
}

// Round 14
// 142.117 us; speedup vs baseline: 1.0184x; 1.0184x over previous
//
#include <hip/hip_runtime.h>
#include <hip/hip_bf16.h>
#include <cstdint>

#define DI __device__ __forceinline__

using u16x8  = __attribute__((ext_vector_type(8))) unsigned short;
using u32x4  = __attribute__((ext_vector_type(4))) unsigned int;
using bf16x8 = __attribute__((ext_vector_type(8))) __bf16;
using f32x4  = __attribute__((ext_vector_type(4))) float;

// ---------- helpers ----------

DI unsigned short f2bf(float f) {           // RNE float -> bf16 bits
  unsigned u = __builtin_bit_cast(unsigned, f);
  u += 0x7fffu + ((u >> 16) & 1u);
  return (unsigned short)(u >> 16);
}
DI float bf2f(unsigned short b) {
  unsigned u = (unsigned)b << 16;
  return __builtin_bit_cast(float, u);
}
DI unsigned cvt_pk_bf16(float lo, float hi) {   // packed {lo,hi} -> 2xbf16 (no builtin on gfx950)
  unsigned r;
  asm("v_cvt_pk_bf16_f32 %0, %1, %2" : "=v"(r) : "v"(lo), "v"(hi));
  return r;
}
// gfx950 cross-lane swaps (both operands read-write):
DI void permlane_swap32(unsigned& a, unsigned& b) {
  asm("v_permlane32_swap_b32 %0, %1" : "+v"(a), "+v"(b));
}
DI void permlane_swap16(unsigned& a, unsigned& b) {
  asm("v_permlane16_swap_b32 %0, %1" : "+v"(a), "+v"(b));
}

DI void gld_lds16(const void* g, void* l) { // async global->LDS, 16B/lane
  __builtin_amdgcn_global_load_lds(
      (const __attribute__((address_space(1))) void*)(uintptr_t)g,
      (__attribute__((address_space(3))) void*)(uint32_t)(uintptr_t)l,
      16, 0, 0);
}

// counted-vmcnt waits (T4). Issued BEFORE a raw s_barrier so that after the
// barrier, every wave's loads older than the N newest are LDS-visible.
DI void wait_vm8() { asm volatile("s_waitcnt vmcnt(8)" ::: "memory"); }
DI void wait_vm4() { asm volatile("s_waitcnt vmcnt(4)" ::: "memory"); }
DI void wait_vm0() { asm volatile("s_waitcnt vmcnt(0)" ::: "memory"); }
DI void sched_fence() { asm volatile("" ::: "memory"); }

// ---------- conversion kernels ----------

__global__ __launch_bounds__(256) void cvt_bf16_kernel(const float* __restrict__ in,
                                                        unsigned short* __restrict__ out, int n) {
  int i = (blockIdx.x * 256 + threadIdx.x) * 8;
  if (i >= n) return;
  float4 v0 = *(const float4*)(in + i);
  float4 v1 = *(const float4*)(in + i + 4);
  u16x8 o;
  o[0] = f2bf(v0.x); o[1] = f2bf(v0.y); o[2] = f2bf(v0.z); o[3] = f2bf(v0.w);
  o[4] = f2bf(v1.x); o[5] = f2bf(v1.y); o[6] = f2bf(v1.z); o[7] = f2bf(v1.w);
  *(u16x8*)(out + i) = o;
}

// in[K][N] fp32 -> out[N][K] bf16
__global__ __launch_bounds__(256) void transpose_cvt_kernel(const float* __restrict__ in,
                                                             unsigned short* __restrict__ out,
                                                             int K, int N) {
  __shared__ float tile[32][33];
  int n0 = blockIdx.x * 32, k0 = blockIdx.y * 32;
  int tx = threadIdx.x & 31, ty = threadIdx.x >> 5;
#pragma unroll
  for (int i = 0; i < 4; ++i)
    tile[ty * 4 + i][tx] = in[(size_t)(k0 + ty * 4 + i) * N + n0 + tx];
  __syncthreads();
#pragma unroll
  for (int i = 0; i < 4; ++i)
    out[(size_t)(n0 + ty * 4 + i) * K + k0 + tx] = f2bf(tile[tx][ty * 4 + i]);
}

// ---------- epilogue helpers for gemm256_qkv (rule #20: static acc indices) ----------

template <int MT>
DI void rope_rows(const f32x4 (&acc)[8][4], unsigned short* __restrict__ dst,
                  int gm0, int h, float qs, int r15, int g4) {
#pragma unroll
  for (int r = 0; r < 4; ++r) {
    int mrow = gm0 + MT * 16 + g4 * 4 + r;
    int b = mrow >> 11, t = mrow & 2047;
    unsigned short* rowp = dst + (((size_t)(b * 16 + h) * 2048 + t) << 6);
    float tf = (float)t;
#pragma unroll
    for (int nt = 0; nt < 2; ++nt) {              // d in [0,32); reg nt+2 holds d+32
      int j = nt * 16 + r15;
      float invf = exp2f((float)j * -0.4152410118609203f);  // 10000^(-j/32)
      float ang = tf * invf;
      float sv, cv;
      sincosf(ang, &sv, &cv);
      float x1 = acc[MT][nt][r], x2 = acc[MT][nt + 2][r];
      rowp[j]      = f2bf((x1 * cv - x2 * sv) * qs);
      rowp[j + 32] = f2bf((x2 * cv + x1 * sv) * qs);
    }
  }
}

template <int P>
DI void vtrans_pass(const f32x4 (&acc)[8][4], short* __restrict__ tb,
                    unsigned short* __restrict__ vhead, int t0, int lane, int r15, int g4) {
#pragma unroll
  for (int np = 0; np < 2; ++np)
#pragma unroll
    for (int mt = 0; mt < 8; ++mt)
#pragma unroll
      for (int pr = 0; pr < 2; ++pr) {
        unsigned pk = cvt_pk_bf16(acc[mt][2 * P + np][2 * pr], acc[mt][2 * P + np][2 * pr + 1]);
        *(unsigned*)(tb + (np * 16 + r15) * 136 + mt * 16 + g4 * 4 + pr * 2) = pk;
      }
#pragma unroll
  for (int cc = 0; cc < 8; ++cc) {
    int dl = (cc & 3) * 8 + (lane >> 3);
    int tc = (lane & 7) * 8 + (cc >> 2) * 64;
    u16x8 vv = *(const u16x8*)(tb + dl * 136 + tc);
    *(u16x8*)(vhead + (size_t)(P * 32 + dl) * 2048 + t0 + tc) = vv;
  }
}

// ---------- QKV GEMM, 256x256 tile, BK=32, 4-slot counted-vmcnt pipeline (T3+T4) ----------

__global__ __launch_bounds__(512, 2)
void gemm256_qkv(const unsigned short* __restrict__ A, const unsigned short* __restrict__ B,
                 unsigned short* __restrict__ q_out, unsigned short* __restrict__ k_out,
                 unsigned short* __restrict__ v_out, int M, int N, int K) {
  __shared__ __align__(16) char smem[4][32768];
  const int tid = threadIdx.x;
  const int lane = tid & 63, wave = tid >> 6;        // 8 waves
  const int wr = wave >> 2, wc = wave & 3;           // 2 x 4 wave grid
  const int r15 = lane & 15, g4 = lane >> 4;

  // bijective XCD swizzle: 192 = 8 * 24; XCD x -> m-tile pair {2x, 2x+1}
  const int id = blockIdx.x;
  const int g = (id & 7) * 24 + (id >> 3);
  const int by = g / 12, bx = g % 12;
  const int m0 = by << 8, n0 = bx << 8;

  const size_t Ks = (size_t)K;
  const unsigned short* aptr = A + (size_t)(m0 + wave * 32 + r15) * Ks + g4 * 8;
  const unsigned short* bptr = B + (size_t)(n0 + wave * 32 + r15) * Ks + g4 * 8;

  f32x4 acc[8][4] = {};
  const int NT = K >> 5;                             // 32

  auto stage = [&](int slot, int tt) {
    const unsigned short* ak = aptr + tt * 32;
    const unsigned short* bk = bptr + tt * 32;
    char* sA = &smem[slot][0]     + wave * 2048;
    char* sB = &smem[slot][16384] + wave * 2048;
    gld_lds16(ak,           sA);
    gld_lds16(ak + 16 * Ks, sA + 1024);
    gld_lds16(bk,           sB);
    gld_lds16(bk + 16 * Ks, sB + 1024);
  };

  auto body = [&](int t) {                            // after wait+barrier
    sched_fence();
    const char* sA = &smem[t & 3][0];
    const char* sB = &smem[t & 3][16384];
    bf16x8 af[8], bfr[4];
#pragma unroll
    for (int mt = 0; mt < 8; ++mt)
      af[mt] = *(const bf16x8*)(sA + (wr * 8 + mt) * 1024 + lane * 16);
#pragma unroll
    for (int nt = 0; nt < 4; ++nt)
      bfr[nt] = *(const bf16x8*)(sB + (wc * 4 + nt) * 1024 + lane * 16);
    if (t + 3 < NT) stage((t + 3) & 3, t + 3);
    __builtin_amdgcn_s_setprio(1);
#pragma unroll
    for (int mt = 0; mt < 8; ++mt)
#pragma unroll
      for (int nt = 0; nt < 4; ++nt)
        acc[mt][nt] = __builtin_amdgcn_mfma_f32_16x16x32_bf16(af[mt], bfr[nt], acc[mt][nt], 0, 0, 0);
    __builtin_amdgcn_s_setprio(0);
  };

  stage(0, 0); stage(1, 1); stage(2, 2);              // prologue: depth-3 prefetch
  for (int t = 0; t < NT - 2; ++t) {
    wait_vm8();
    __builtin_amdgcn_s_barrier();
    body(t);
  }
  wait_vm4();
  __builtin_amdgcn_s_barrier();
  body(NT - 2);
  wait_vm0();
  __builtin_amdgcn_s_barrier();
  body(NT - 1);

  __syncthreads();                                    // drain before smem reuse (epilogue)

  const int gm0 = m0 + wr * 128, gn0 = n0 + wc * 64;
  const int region = gn0 >> 10;                       // 0=q 1=k 2=v
  const int h = (gn0 & 1023) >> 6;
  if (region <= 1) {
    unsigned short* dst = (region == 0) ? q_out : k_out;
    const float qs = (region == 0) ? (0.125f * 1.44269504088896341f) : 1.0f;
    rope_rows<0>(acc, dst, gm0, h, qs, r15, g4);
    rope_rows<1>(acc, dst, gm0, h, qs, r15, g4);
    rope_rows<2>(acc, dst, gm0, h, qs, r15, g4);
    rope_rows<3>(acc, dst, gm0, h, qs, r15, g4);
    rope_rows<4>(acc, dst, gm0, h, qs, r15, g4);
    rope_rows<5>(acc, dst, gm0, h, qs, r15, g4);
    rope_rows<6>(acc, dst, gm0, h, qs, r15, g4);
    rope_rows<7>(acc, dst, gm0, h, qs, r15, g4);
  } else {
    const int b = gm0 >> 11, t0 = gm0 & 2047;
    unsigned short* vhead = v_out + ((size_t)(b * 16 + h) * 64) * 2048;
    short* tb = (short*)(&smem[0][0] + wave * 16384);
    vtrans_pass<0>(acc, tb, vhead, t0, lane, r15, g4);
    vtrans_pass<1>(acc, tb, vhead, t0, lane, r15, g4);
  }
}

// ---------- out-proj GEMM: 128x128 tile, BK=32, same 4-slot counted-vmcnt pipeline ----------

__global__ __launch_bounds__(256, 2)
void gemm_proj(const unsigned short* __restrict__ A, const unsigned short* __restrict__ B,
               float* __restrict__ c_out, int M, int N, int K) {
  __shared__ __align__(16) char smem[4][16384];
  const int tid = threadIdx.x;
  const int lane = tid & 63, wave = tid >> 6;         // 4 waves
  const int wm = wave >> 1, wn = wave & 1;
  const int r15 = lane & 15, g4 = lane >> 4;

  const int id = blockIdx.x;                          // 256 blocks: XCD band swizzle
  const int xcd = id & 7, rr = id >> 3;
  const int m0 = rr << 7, n0 = xcd << 7;

  const size_t Ks = (size_t)K;
  const unsigned short* aptr = A + (size_t)(m0 + wave * 32 + r15) * Ks + g4 * 8;
  const unsigned short* bptr = B + (size_t)(n0 + wave * 32 + r15) * Ks + g4 * 8;

  f32x4 acc[4][4] = {};
  const int NT = K >> 5;                              // 32

  auto stage = [&](int slot, int tt) {
    const unsigned short* ak = aptr + tt * 32;
    const unsigned short* bk = bptr + tt * 32;
    char* sA = &smem[slot][0]    + wave * 2048;
    char* sB = &smem[slot][8192] + wave * 2048;
    gld_lds16(ak,           sA);
    gld_lds16(ak + 16 * Ks, sA + 1024);
    gld_lds16(bk,           sB);
    gld_lds16(bk + 16 * Ks, sB + 1024);
  };

  auto body = [&](int t) {
    sched_fence();
    const char* sA = &smem[t & 3][0];
    const char* sB = &smem[t & 3][8192];
    bf16x8 af[4], bfr[4];
#pragma unroll
    for (int mt = 0; mt < 4; ++mt)
      af[mt] = *(const bf16x8*)(sA + (wm * 4 + mt) * 1024 + lane * 16);
#pragma unroll
    for (int nt = 0; nt < 4; ++nt)
      bfr[nt] = *(const bf16x8*)(sB + (wn * 4 + nt) * 1024 + lane * 16);
    if (t + 3 < NT) stage((t + 3) & 3, t + 3);
    __builtin_amdgcn_s_setprio(1);
#pragma unroll
    for (int mt = 0; mt < 4; ++mt)
#pragma unroll
      for (int nt = 0; nt < 4; ++nt)
        acc[mt][nt] = __builtin_amdgcn_mfma_f32_16x16x32_bf16(af[mt], bfr[nt], acc[mt][nt], 0, 0, 0);
    __builtin_amdgcn_s_setprio(0);
  };

  stage(0, 0); stage(1, 1); stage(2, 2);
  for (int t = 0; t < NT - 2; ++t) {
    wait_vm8();
    __builtin_amdgcn_s_barrier();
    body(t);
  }
  wait_vm4();
  __builtin_amdgcn_s_barrier();
  body(NT - 2);
  wait_vm0();
  __builtin_amdgcn_s_barrier();
  body(NT - 1);

  const int gm0 = m0 + wm * 64, gn0 = n0 + wn * 64;
#pragma unroll
  for (int mt = 0; mt < 4; ++mt)
#pragma unroll
    for (int r = 0; r < 4; ++r) {
      int mrow = gm0 + mt * 16 + g4 * 4 + r;
      float* rowp = c_out + (size_t)mrow * N + gn0;
#pragma unroll
      for (int nt = 0; nt < 4; ++nt)
        rowp[nt * 16 + r15] = acc[mt][nt][r];
    }
}

// ---------- causal flash attention, v8 ----------
// v7 math + pipeline, rescheduled for tail elimination: every q-block J splits into
// nc = 1/2/3/4 chunks (J<=3 / 4-7 / 8-11 / 12-15), chunk c covers kv-tiles
// [c*T/nc, (c+1)*T/nc), T = 2J+2 -> ALL chunks are 2..8 tiles. Grid = 32 bh x 40
// chunks = 1280 blocks (5/CU, real backfill). Diagonal provably in last chunk.
// RBMAP40 = longest-first dispatch (LPT hint). Partials: 1152 x 16KB, stored in
// d_out (scratch until gemm_proj overwrites it; first 1024) then xb (rest).

__device__ const int RBMAP40[40] = {
  3, 10, 11, 20, 21, 22, 23, 33, 35, 36, 37, 38, 39,       // len 8
  8, 9, 16, 17, 18, 19, 25, 27, 28, 29, 30, 31, 32, 34,    // len 7
  2, 6, 7, 12, 13, 14, 15, 24, 26,                         // len 6
  4, 5,                                                     // len 5
  1,                                                        // len 4
  0                                                         // len 2
};

DI unsigned short* part_ptr(unsigned short* p0, unsigned short* p1, int sidx) {
  return (sidx < 1024) ? p0 + (size_t)sidx * 8192 : p1 + (size_t)(sidx - 1024) * 8192;
}

__global__ __launch_bounds__(256)
void attn_fused(const unsigned short* __restrict__ qb, const unsigned short* __restrict__ kb,
                const unsigned short* __restrict__ vt, unsigned short* __restrict__ attno,
                unsigned short* __restrict__ pO0, unsigned short* __restrict__ pO1,
                float* __restrict__ pml) {
  __shared__ __align__(16) char ksm[3][8192];
  __shared__ __align__(16) char vsm[3][8192];

  const int tid = threadIdx.x, lane = tid & 63, wave = tid >> 6;
  const int r15 = lane & 15, g4 = lane >> 4;

  // XCD swizzle: 1280 = 8 * 160; XCD x hosts bh [4x, 4x+4)
  const int wg = blockIdx.x;                  // 0..1279
  const int swz = (wg & 7) * 160 + (wg >> 3);
  const int bh = swz / 40;
  const int rb = RBMAP40[swz % 40];
  int J, c, nc;
  if (rb < 4)       { J = rb;                 c = 0;            nc = 1; }
  else if (rb < 12) { J = 4 + ((rb - 4) >> 1);  c = (rb - 4) & 1;  nc = 2; }
  else if (rb < 24) { int r = rb - 12; J = 8 + r / 3;  c = r % 3;  nc = 3; }
  else              { int r = rb - 24; J = 12 + (r >> 2); c = r & 3; nc = 4; }
  const int T = 2 * J + 2;
  const int kt0 = (c * T) / nc;
  const int ktN = ((c + 1) * T) / nc;
  const int NTW = ktN - kt0;                  // 2..8
  const bool multi = (nc > 1);
  const int q0w = (J << 7) + wave * 32;

  const size_t hb = (size_t)bh * 2048 * 64;
  const unsigned short* Qp = qb + hb;
  const unsigned short* Kp = kb + hb;
  const unsigned short* Vp = vt + hb;         // [64][2048]

  bf16x8 qf[2][2];
#pragma unroll
  for (int mq = 0; mq < 2; ++mq)
#pragma unroll
    for (int kc = 0; kc < 2; ++kc)
      qf[mq][kc] = *(const bf16x8*)(Qp + (size_t)(q0w + mq * 16 + r15) * 64 + kc * 32 + g4 * 8);

  f32x4 o[2][4] = {};
  float mr[2] = {-INFINITY, -INFINITY};
  float lr[2] = {0.f, 0.f};

  auto stage = [&](int slot, int kt) {
    const int kv0 = kt << 6;
#pragma unroll
    for (int i = 0; i < 2; ++i) {
      int f = wave * 2 + i;
      int nt = f >> 1, kc = f & 1;
      gld_lds16(Kp + (size_t)(kv0 + nt * 16 + r15) * 64 + kc * 32 + g4 * 8, &ksm[slot][f * 1024]);
      gld_lds16(Vp + (size_t)(nt * 16 + r15) * 2048 + kv0 + kc * 32 + g4 * 8, &vsm[slot][f * 1024]);
    }
  };

  auto process = [&](int slot, int kv0, bool mask) {
    bf16x8 kf[8];
#pragma unroll
    for (int i = 0; i < 8; ++i)
      kf[i] = *(const bf16x8*)(&ksm[slot][i * 1024] + lane * 16);

    f32x4 s[4][2] = {};
    __builtin_amdgcn_s_setprio(1);
#pragma unroll
    for (int nt = 0; nt < 4; ++nt)
#pragma unroll
      for (int kc = 0; kc < 2; ++kc) {
        s[nt][0] = __builtin_amdgcn_mfma_f32_16x16x32_bf16(kf[nt * 2 + kc], qf[0][kc], s[nt][0], 0, 0, 0);
        s[nt][1] = __builtin_amdgcn_mfma_f32_16x16x32_bf16(kf[nt * 2 + kc], qf[1][kc], s[nt][1], 0, 0, 0);
      }
    __builtin_amdgcn_s_setprio(0);

    if (mask) {
#pragma unroll
      for (int nt = 0; nt < 4; ++nt)
#pragma unroll
        for (int mq = 0; mq < 2; ++mq)
#pragma unroll
          for (int r = 0; r < 4; ++r)
            if (kv0 + nt * 16 + g4 * 4 + r > q0w + mq * 16 + r15) s[nt][mq][r] = -1e9f;
    }

    bf16x8 pa[2][2];
#pragma unroll
    for (int mq = 0; mq < 2; ++mq) {
      float m0 = fmaxf(fmaxf(s[0][mq][0], s[0][mq][1]), fmaxf(s[0][mq][2], s[0][mq][3]));
      float m1 = fmaxf(fmaxf(s[1][mq][0], s[1][mq][1]), fmaxf(s[1][mq][2], s[1][mq][3]));
      float m2 = fmaxf(fmaxf(s[2][mq][0], s[2][mq][1]), fmaxf(s[2][mq][2], s[2][mq][3]));
      float m3 = fmaxf(fmaxf(s[3][mq][0], s[3][mq][1]), fmaxf(s[3][mq][2], s[3][mq][3]));
      float mx = fmaxf(fmaxf(m0, m1), fmaxf(m2, m3));
      mx = fmaxf(mx, __shfl_xor(mx, 16));
      mx = fmaxf(mx, __shfl_xor(mx, 32));
      float mnew;
      if (!__all(mx <= mr[mq] + 8.f)) {
        mnew = fmaxf(mr[mq], mx);
        float fsc = exp2f(mr[mq] - mnew);
        mr[mq] = mnew;
        lr[mq] *= fsc;
#pragma unroll
        for (int r = 0; r < 4; ++r) {
          float fr = __shfl(fsc, (g4 << 2) + r);
#pragma unroll
          for (int dt = 0; dt < 4; ++dt) o[mq][dt][r] *= fr;
        }
      } else {
        mnew = mr[mq];
      }
      float t0 = 0.f, t1 = 0.f, t2 = 0.f, t3 = 0.f;
#pragma unroll
      for (int nt = 0; nt < 4; ++nt) {
        float p0 = exp2f(s[nt][mq][0] - mnew);
        float p1 = exp2f(s[nt][mq][1] - mnew);
        float p2 = exp2f(s[nt][mq][2] - mnew);
        float p3 = exp2f(s[nt][mq][3] - mnew);
        s[nt][mq][0] = p0; s[nt][mq][1] = p1; s[nt][mq][2] = p2; s[nt][mq][3] = p3;
        if (nt == 0) t0 = (p0 + p1) + (p2 + p3);
        if (nt == 1) t1 = (p0 + p1) + (p2 + p3);
        if (nt == 2) t2 = (p0 + p1) + (p2 + p3);
        if (nt == 3) t3 = (p0 + p1) + (p2 + p3);
      }
      float ps = (t0 + t1) + (t2 + t3);
      ps += __shfl_xor(ps, 16);
      ps += __shfl_xor(ps, 32);
      lr[mq] += ps;
      unsigned p32[4][2];
#pragma unroll
      for (int nt = 0; nt < 4; ++nt) {
        p32[nt][0] = cvt_pk_bf16(s[nt][mq][0], s[nt][mq][1]);
        p32[nt][1] = cvt_pk_bf16(s[nt][mq][2], s[nt][mq][3]);
      }
#pragma unroll
      for (int kc = 0; kc < 2; ++kc) {
        u32x4 w;
#pragma unroll
        for (int pi = 0; pi < 2; ++pi) {
          unsigned a = p32[2 * kc][pi], b = p32[2 * kc + 1][pi];
          permlane_swap32(a, b);
          permlane_swap16(a, b);
          w[pi] = a;
          w[2 + pi] = b;
        }
        pa[mq][kc] = __builtin_bit_cast(bf16x8, w);
      }
    }

    bf16x8 vf[8];
#pragma unroll
    for (int i = 0; i < 8; ++i)
      vf[i] = *(const bf16x8*)(&vsm[slot][i * 1024] + lane * 16);

    __builtin_amdgcn_s_setprio(1);
#pragma unroll
    for (int kc = 0; kc < 2; ++kc)
#pragma unroll
      for (int dt = 0; dt < 4; ++dt) {
        o[0][dt] = __builtin_amdgcn_mfma_f32_16x16x32_bf16(pa[0][kc], vf[dt * 2 + kc], o[0][dt], 0, 0, 0);
        o[1][dt] = __builtin_amdgcn_mfma_f32_16x16x32_bf16(pa[1][kc], vf[dt * 2 + kc], o[1][dt], 0, 0, 0);
      }
    __builtin_amdgcn_s_setprio(0);
  };

  // 3-slot counted-vmcnt pipeline, depth-2 prefetch
  stage(0, kt0);
  if (NTW > 1) stage(1, kt0 + 1);
  for (int i = 0; i < NTW; ++i) {
    if (i + 1 < NTW) wait_vm4(); else wait_vm0();
    __builtin_amdgcn_s_barrier();
    sched_fence();
    if (i + 2 < NTW) stage((i + 2) % 3, kt0 + i + 2);
    const int kv0 = (kt0 + i) << 6;
    if (kv0 <= q0w + 31)
      process(i % 3, kv0, kv0 + 63 > q0w);
  }

  if (!multi) {
    const int b = bh >> 4, h = bh & 15;
#pragma unroll
    for (int mq = 0; mq < 2; ++mq) {
      float inv = 1.f / lr[mq];
#pragma unroll
      for (int r = 0; r < 4; ++r) {
        float ir = __shfl(inv, (g4 << 2) + r);
        int q = q0w + mq * 16 + g4 * 4 + r;
        unsigned short* rowp = attno + (size_t)(b * 2048 + q) * 1024 + h * 64;
#pragma unroll
        for (int dt = 0; dt < 4; ++dt)
          rowp[dt * 16 + r15] = f2bf(o[mq][dt][r] * ir);
      }
    }
  } else {
    // partial slot: J 4-7 -> (J-4)*2+c; 8-11 -> 8+(J-8)*3+c; 12-15 -> 20+(J-12)*4+c
    const int slot = (J < 8) ? (J - 4) * 2 + c
                   : (J < 12) ? 8 + (J - 8) * 3 + c
                              : 20 + (J - 12) * 4 + c;
    const int sidx = bh * 36 + slot;
    unsigned short* po = part_ptr(pO0, pO1, sidx) + wave * 32 * 64;
#pragma unroll
    for (int mq = 0; mq < 2; ++mq)
#pragma unroll
      for (int r = 0; r < 4; ++r)
#pragma unroll
        for (int dt = 0; dt < 4; ++dt)
          po[(mq * 16 + g4 * 4 + r) * 64 + dt * 16 + r15] = f2bf(o[mq][dt][r]);
    if (g4 == 0) {
      float* pm = pml + sidx * 256 + wave * 32;
#pragma unroll
      for (int mq = 0; mq < 2; ++mq) {
        pm[mq * 16 + r15] = mr[mq];
        pm[128 + mq * 16 + r15] = lr[mq];
      }
    }
  }
}

// ---------- combine partials for q-blocks J>=4 (nc = 2..4 chunks) ----------
__global__ __launch_bounds__(256)
void attn_combine(unsigned short* __restrict__ pO0, unsigned short* __restrict__ pO1,
                  const float* __restrict__ pml, unsigned short* __restrict__ attno) {
  const int bx = blockIdx.x;                 // 0..383 = 32 bh x 12 multi-J
  const int bh = bx / 12, jj = bx % 12, J = 4 + jj;
  const int nc = (jj < 4) ? 2 : (jj < 8) ? 3 : 4;
  const int slotbase = (jj < 4) ? jj * 2 : (jj < 8) ? 8 + (jj - 4) * 3 : 20 + (jj - 8) * 4;
  const int t = threadIdx.x;
  const int row = t >> 1;                    // 0..127
  const int dh = (t & 1) << 5;               // 0 or 32

  // pass 1: global max and denom (static indices via bounded unroll)
  float mv[4], lv[4];
  float mg = -INFINITY;
#pragma unroll
  for (int cc = 0; cc < 4; ++cc)
    if (cc < nc) {
      const int sidx = bh * 36 + slotbase + cc;
      mv[cc] = pml[sidx * 256 + row];
      lv[cc] = pml[sidx * 256 + 128 + row];
      mg = fmaxf(mg, mv[cc]);
    }
  float denom = 0.f;
#pragma unroll
  for (int cc = 0; cc < 4; ++cc)
    if (cc < nc) {
      mv[cc] = exp2f(mv[cc] - mg);
      denom += lv[cc] * mv[cc];
    }
  const float inv = 1.f / denom;

  // pass 2: weighted accumulate of O partials
  float av[32] = {};
#pragma unroll
  for (int cc = 0; cc < 4; ++cc)
    if (cc < nc) {
      const int sidx = bh * 36 + slotbase + cc;
      const unsigned short* op = part_ptr(pO0, pO1, sidx) + row * 64 + dh;
      const float w = mv[cc] * inv;
#pragma unroll
      for (int dd = 0; dd < 32; dd += 8) {
        u16x8 a = *(const u16x8*)(op + dd);
#pragma unroll
        for (int e = 0; e < 8; ++e)
          av[dd + e] += bf2f(a[e]) * w;
      }
    }

  const int b = bh >> 4, h = bh & 15;
  const int q = J * 128 + row;
  unsigned short* dst = attno + (size_t)(b * 2048 + q) * 1024 + h * 64 + dh;
#pragma unroll
  for (int dd = 0; dd < 32; dd += 8) {
    u16x8 ov;
#pragma unroll
    for (int e = 0; e < 8; ++e)
      ov[e] = f2bf(av[dd + e]);
    *(u16x8*)(dst + dd) = ov;
  }
}

// ---------- launcher ----------

extern "C" void kernel_launch(void* const* d_in, const int* in_sizes, int n_in,
                              void* d_out, int out_size, void* d_ws, size_t ws_size,
                              hipStream_t stream) {
  const float* x     = (const float*)d_in[0];
  const float* w_qkv = (const float*)d_in[1];
  const float* w_out = (const float*)d_in[2];
  float* out = (float*)d_out;

  char* ws = (char*)d_ws;
  unsigned short* xb  = (unsigned short*)(ws);                     // 8 MB  x bf16 (dead after gemm_qkv)
  unsigned short* wqT = (unsigned short*)(ws + (8u << 20));        // 6 MB  w_qkv^T (dead after gemm_qkv)
  unsigned short* woT = (unsigned short*)(ws + (14u << 20));       // 2 MB  w_out^T
  unsigned short* qb  = (unsigned short*)(ws + (16u << 20));       // 8 MB  q (roped, scaled)
  unsigned short* kb  = (unsigned short*)(ws + (24u << 20));       // 8 MB  k (roped)
  unsigned short* vt  = (unsigned short*)(ws + (32u << 20));       // 8 MB  v transposed [32][64][2048]
  unsigned short* ao  = (unsigned short*)(ws + (40u << 20));       // 8 MB  attn out [4096][1024]
  // partial O: sidx<1024 in d_out (16 MB scratch until gemm_proj), rest in xb
  unsigned short* pO0 = (unsigned short*)d_out;
  unsigned short* pO1 = xb;
  float*          pml = (float*)wqT;                               // partial m/l f32 (1.2 MB, reuse)

  cvt_bf16_kernel<<<2048, 256, 0, stream>>>(x, xb, 4096 * 1024);
  transpose_cvt_kernel<<<dim3(96, 32), 256, 0, stream>>>(w_qkv, wqT, 1024, 3072);
  transpose_cvt_kernel<<<dim3(32, 32), 256, 0, stream>>>(w_out, woT, 1024, 1024);
  gemm256_qkv<<<192, 512, 0, stream>>>(xb, wqT, qb, kb, vt, 4096, 3072, 1024);
  attn_fused<<<1280, 256, 0, stream>>>(qb, kb, vt, ao, pO0, pO1, pml);
  attn_combine<<<384, 256, 0, stream>>>(pO0, pO1, pml, ao);
  gemm_proj<<<256, 256, 0, stream>>>(ao, woT, out, 4096, 1024, 1024);
}